// Round 8
// baseline (244.116 us; speedup 1.0000x reference)
//
#include <hip/hip_runtime.h>
#include <stdint.h>

// ---------------------------------------------------------------------------
// NIVR: coord-MLP over 512x512 grid.
//   pre_kernel (1024 blocks): blocks 0..511 compute the time branch inline
//     (redundant per block, ~4us device-wide) and write Txp = tvec + posenc_x
//     fold, plus Ty; blocks 512..1023: W2f -> bf16 W2s (32x32x16 frags).
//   main: h1 = relu(Txp[x]+Ty[y]); layer2 via MFMA bf16 32x32x16 (swapped
//     operands => acc holds h2^T); fused layer3 epilogue. Out [3][N].
//
// R17 vs R16: R16 (BM=128, 1 blk/CU) serialized its 12k-cyc fill behind a
// single barrier (~40us of matrix-idle) and ran 2 waves/SIMD. Reg caps are
// now calibrated (2048/lane/SIMD): 4 waves/SIMD => 128 combined regs.
// BM=64 + 32x32 frags is the unique point where the FULL depth-1 A+B
// register pipeline fits at 4 waves/SIMD:
//   acc 2x2xf32x16=64 + areg[2][2]=16 + breg[2][2]=16 + misc ~15 = 111<=128.
// LDS 64KB A (whole K, 1 barrier) + 6KB part = 70KB => 2 blocks/CU: fill of
// one block overlaps kloop of the other; 4 waves/SIMD restores TLP hiding.
// Cost: B traffic back to 8MB/CU (58us L2 floor, ~= matrix 55) -- accepted.
// Also: total-main has been ~60-75us in EVERY round regardless of pre =>
// harness fixed cost; pre simplified back to one kernel, tvec folded.
// ---------------------------------------------------------------------------

typedef short bf16x8 __attribute__((ext_vector_type(8)));
typedef float f32x16 __attribute__((ext_vector_type(16)));

#define PI_F 3.14159265358979323846f
#define SIDE 512
#define NPIX (SIDE * SIDE)

__device__ __forceinline__ unsigned short f2bf(float f) {
  unsigned int u = __float_as_uint(f);
  u += 0x7fffu + ((u >> 16) & 1u);
  return (unsigned short)(u >> 16);
}

// ---------------------------------------------------------------------------
// pre: 1024 blocks x 512 threads.
//   b in [0,512)    : time branch (redundant per block) -> tvec[t];
//                     Txp[b][k] = tvec[k] + sum_l enc[l] W1f[l][k]
//                     Ty [b][k] =           sum_l enc[l] W1f[20+l][k]
//   b in [512,1024) : W2f -> bf16 W2s, 32x32x16 A-operand frags
//                     (R14/R15-verified layout):
//                     W2s[kstep*8192 + nt32*512 + (hi*32+lo)*8 + j]
//                       = bf16(W2f[kstep*16 + hi*8 + j][nt32*32 + lo])
// ---------------------------------------------------------------------------
__global__ void pre_kernel(const float* __restrict__ W1p, const float* __restrict__ b1p,
                           const float* __restrict__ W2p, const float* __restrict__ b2p,
                           const float* __restrict__ W1f, const float* __restrict__ b1f,
                           const float* __restrict__ W2f, const int* __restrict__ idx,
                           float* __restrict__ Txp, float* __restrict__ Ty,
                           unsigned short* __restrict__ W2s) {
  const int b = blockIdx.x;
  const int t = threadIdx.x;

  if (b >= 512) {
    const int k = b - 512, n = t;
    const int kstep = k >> 4, hi = (k >> 3) & 1, j = k & 7;
    const int nt32 = n >> 5, lo = n & 31;
    W2s[kstep * 8192 + nt32 * 512 + (hi * 32 + lo) * 8 + j] = f2bf(W2f[k * 512 + n]);
    return;
  }

  __shared__ float enc[20];
  __shared__ float r_s[32];
  __shared__ float h_s[256];
  __shared__ float phi_s[128];

  if (t < 10) {
    float u = (float)b / 512.0f;
    float ang = u * ldexpf(PI_F, t);
    enc[t] = sinf(ang);
    enc[10 + t] = cosf(ang);
  }
  if (t >= 32 && t < 48) {
    const int l = t - 32;
    float tt = (float)idx[0] / 300.0f;
    float ang = tt * ldexpf(PI_F, l);
    r_s[l] = sinf(ang);
    r_s[16 + l] = cosf(ang);
  }
  __syncthreads();
  if (t < 256) {
    float a = b1p[t];
#pragma unroll
    for (int i = 0; i < 32; ++i) a += r_s[i] * W1p[i * 256 + t];
    h_s[t] = fmaxf(a, 0.f);
  }
  __syncthreads();
  if (t < 128) {
    float a = b2p[t];
    for (int i = 0; i < 256; ++i) a += h_s[i] * W2p[i * 128 + t];
    phi_s[t] = a;
  }
  __syncthreads();
  {
    float tv = b1f[t];
    for (int p = 0; p < 128; ++p) tv += phi_s[p] * W1f[(40 + p) * 512 + t];
    float ax = tv, ay = 0.f;
#pragma unroll
    for (int l = 0; l < 20; ++l) {
      ax += enc[l] * W1f[l * 512 + t];
      ay += enc[l] * W1f[(20 + l) * 512 + t];
    }
    Txp[b * 512 + t] = ax;
    Ty[b * 512 + t] = ay;
  }
}

// ---------------------------------------------------------------------------
// Main fused kernel. Block = 512 thr (8 waves), BM=64 (8x8 patch), BN=512,
// K=512 in 32 steps of 16 k. Whole A tile (64KB) resident in LDS.
// Wave w owns n-cols [w*64, +64) (no B duplication within a block).
// Per step per wave: 2 A ds_read_b128 + 2 B 16B loads (both prefetched one
// step ahead into areg/breg rotations), 4 MFMA 32x32x16.
// A storage (shorts): elem (p,k) at (k>>4)*1024 + (p>>5)*512
//                      + ((k>>3)&1)*256 + (p&31)*8 + (k&7)
//   => frag (step, mf) read at lane l: step*1024 + mf*512 + l*8 (contig 1KB).
// acc[mf][nn] reg r: h2[pix = mf*32 + (lane&31)]
//                   [n = w*64 + nn*32 + (r&3) + 8*(r>>2) + 4*(lane>>5)]
// ---------------------------------------------------------------------------
__global__ __launch_bounds__(512, 4) void main_kernel(
    const float* __restrict__ Txp, const float* __restrict__ Ty,
    const unsigned short* __restrict__ W2s, const float* __restrict__ b2f,
    const float* __restrict__ W3f, const float* __restrict__ b3f,
    float* __restrict__ out) {
  __shared__ __attribute__((aligned(16))) unsigned short Ab[32 * 1024];  // 64KB: 32 steps x (64 pix x 16 k)
  __shared__ float part[8][64][3];                                       // 6KB

  const int t = threadIdx.x;
  const int w = t >> 6;            // wave id 0..7 (owns n-slice [w*64,+64))
  const int lane = t & 63;
  const int lo = lane & 31;
  const int hi = lane >> 5;
  const int x0 = blockIdx.x * 8, y0 = blockIdx.y * 8;

  // per-wave K-phase offset over the 32 steps (SGPR)
  const int kofs = __builtin_amdgcn_readfirstlane((w * 4) & 31);

  // B: frag (kstep, nn) at W2s + kstep*8192 + (w*2+nn)*512 + lane*8
  const unsigned short* bptr = W2s + (w * 2) * 512 + lane * 8;

  // ---- A fill (whole tile, once): thread (p = t>>3, s = t&7) covers pixel
  // p (0..63), k = g32*32 + s*4..+3 for g32 = 0..15.
  // write addr (shorts): (g32*2 + (s>>2))*1024 + (p>>5)*512
  //                      + ((s>>1)&1)*256 + (p&31)*8 + (s&1)*4
  {
    const int p = t >> 3, s = t & 7;
    const int xi = x0 + (p >> 3), yi = y0 + (p & 7);
    const float* txp = Txp + xi * 512 + s * 4;
    const float* typ = Ty + yi * 512 + s * 4;
    const int abase = (s >> 2) * 1024 + (p >> 5) * 512 + ((s >> 1) & 1) * 256 +
                      (p & 31) * 8 + (s & 1) * 4;
#pragma unroll
    for (int g = 0; g < 16; ++g) {
      float4 a = *(const float4*)(txp + g * 32);
      float4 b = *(const float4*)(typ + g * 32);
      float v0 = fmaxf(a.x + b.x, 0.f);
      float v1 = fmaxf(a.y + b.y, 0.f);
      float v2 = fmaxf(a.z + b.z, 0.f);
      float v3 = fmaxf(a.w + b.w, 0.f);
      uint2 pk;
      asm("v_cvt_pk_bf16_f32 %0, %1, %2" : "=v"(pk.x) : "v"(v0), "v"(v1));
      asm("v_cvt_pk_bf16_f32 %0, %1, %2" : "=v"(pk.y) : "v"(v2), "v"(v3));
      *(uint2*)&Ab[g * 2048 + abase] = pk;
    }
  }

  // ---- B pipeline init: depth 1 (2 buffers). breg[ks&1] used at pos ks. ----
  bf16x8 breg[2][2];
#pragma unroll
  for (int nn = 0; nn < 2; ++nn)
    breg[0][nn] = *(const bf16x8*)(bptr + kofs * 8192 + nn * 512);

  f32x16 acc[2][2];
#pragma unroll
  for (int mf = 0; mf < 2; ++mf)
#pragma unroll
    for (int nn = 0; nn < 2; ++nn)
#pragma unroll
      for (int r = 0; r < 16; ++r) acc[mf][nn][r] = 0.f;

  __syncthreads();  // publishes A; the only barrier before the epilogue

  // ---- A pipeline init: depth 1. areg[ks&1] used at pos ks. ----
  bf16x8 areg[2][2];
#pragma unroll
  for (int mf = 0; mf < 2; ++mf)
    areg[0][mf] = *(const bf16x8*)&Ab[kofs * 1024 + mf * 512 + lane * 8];

  // ---- K-loop: 32 steps, fully unrolled, no barriers, wave-staggered.
  // Loads for step ks+1 issued before this step's MFMAs. ----
#pragma unroll
  for (int ks = 0; ks < 32; ++ks) {
    const int kkl = (ks + kofs) & 31;
    if (ks < 31) {
      const int knl = (kkl + 1) & 31;
#pragma unroll
      for (int nn = 0; nn < 2; ++nn)
        breg[(ks + 1) & 1][nn] =
            *(const bf16x8*)(bptr + knl * 8192 + nn * 512);
      const unsigned short* arow = &Ab[knl * 1024 + lane * 8];
#pragma unroll
      for (int mf = 0; mf < 2; ++mf)
        areg[(ks + 1) & 1][mf] = *(const bf16x8*)&arow[mf * 512];
    }
    __builtin_amdgcn_s_setprio(1);
#pragma unroll
    for (int nn = 0; nn < 2; ++nn) {
      acc[0][nn] = __builtin_amdgcn_mfma_f32_32x32x16_bf16(
          breg[ks & 1][nn], areg[ks & 1][0], acc[0][nn], 0, 0, 0);
      acc[1][nn] = __builtin_amdgcn_mfma_f32_32x32x16_bf16(
          breg[ks & 1][nn], areg[ks & 1][1], acc[1][nn], 0, 0, 0);
    }
    __builtin_amdgcn_s_setprio(0);
  }

  // ---- epilogue: h2 = relu(acc + b2f); rgb partial = h2 @ W3f.
  // Lane: pixels mf*32+lo, n-cols w*64 + nn*32 + rq*8 + hi*4 + e.
  // shfl_xor(32) combines hi-halves. ----
  {
    float p3[2][3];
#pragma unroll
    for (int mf = 0; mf < 2; ++mf) {
      p3[mf][0] = 0.f; p3[mf][1] = 0.f; p3[mf][2] = 0.f;
    }
#pragma unroll
    for (int nn = 0; nn < 2; ++nn) {
#pragma unroll
      for (int rq = 0; rq < 4; ++rq) {
        const int n0 = w * 64 + nn * 32 + rq * 8 + hi * 4;
        float4 bv = *(const float4*)&b2f[n0];
        float4 u0 = *(const float4*)&W3f[n0 * 3 + 0];
        float4 u1 = *(const float4*)&W3f[n0 * 3 + 4];
        float4 u2 = *(const float4*)&W3f[n0 * 3 + 8];
#pragma unroll
        for (int mf = 0; mf < 2; ++mf) {
          float h0 = fmaxf(acc[mf][nn][rq * 4 + 0] + bv.x, 0.f);
          float h1 = fmaxf(acc[mf][nn][rq * 4 + 1] + bv.y, 0.f);
          float h2 = fmaxf(acc[mf][nn][rq * 4 + 2] + bv.z, 0.f);
          float h3 = fmaxf(acc[mf][nn][rq * 4 + 3] + bv.w, 0.f);
          p3[mf][0] += h0 * u0.x + h1 * u0.w + h2 * u1.z + h3 * u2.y;
          p3[mf][1] += h0 * u0.y + h1 * u1.x + h2 * u1.w + h3 * u2.z;
          p3[mf][2] += h0 * u0.z + h1 * u1.y + h2 * u2.x + h3 * u2.w;
        }
      }
    }
#pragma unroll
    for (int mf = 0; mf < 2; ++mf)
#pragma unroll
      for (int cc = 0; cc < 3; ++cc)
        p3[mf][cc] += __shfl_xor(p3[mf][cc], 32, 64);
    if (hi == 0) {
#pragma unroll
      for (int mf = 0; mf < 2; ++mf)
#pragma unroll
        for (int cc = 0; cc < 3; ++cc)
          part[w][mf * 32 + lo][cc] = p3[mf][cc];
    }
  }
  __syncthreads();
  if (t < 192) {
    const int c = t >> 6, pp = t & 63;
    float sum = b3f[c];
#pragma unroll
    for (int ww = 0; ww < 8; ++ww) sum += part[ww][pp][c];
    out[c * NPIX + (x0 + (pp >> 3)) * 512 + (y0 + (pp & 7))] = sum;
  }
}

// ---------------------------------------------------------------------------
// Inputs: 0 coords (unused), 1 W1p, 2 b1p, 3 W2p, 4 b2p, 5 W1f, 6 b1f,
//         7 W2f, 8 b2f, 9 W3f, 10 b3f, 11 idx
// ---------------------------------------------------------------------------
extern "C" void kernel_launch(void* const* d_in, const int* in_sizes, int n_in,
                              void* d_out, int out_size, void* d_ws, size_t ws_size,
                              hipStream_t stream) {
  const float* W1p = (const float*)d_in[1];
  const float* b1p = (const float*)d_in[2];
  const float* W2p = (const float*)d_in[3];
  const float* b2p = (const float*)d_in[4];
  const float* W1f = (const float*)d_in[5];
  const float* b1f = (const float*)d_in[6];
  const float* W2f = (const float*)d_in[7];
  const float* b2f = (const float*)d_in[8];
  const float* W3f = (const float*)d_in[9];
  const float* b3f = (const float*)d_in[10];
  const int* idx = (const int*)d_in[11];
  float* out = (float*)d_out;

  char* ws = (char*)d_ws;
  float* Txp = (float*)ws;                                   // 1 MB
  float* Ty = (float*)(ws + (1u << 20));                     // 1 MB
  unsigned short* W2s = (unsigned short*)(ws + (2u << 20));  // 512 KB

  hipLaunchKernelGGL(pre_kernel, dim3(1024), dim3(512), 0, stream,
                     W1p, b1p, W2p, b2p, W1f, b1f, W2f, idx, Txp, Ty, W2s);
  hipLaunchKernelGGL(main_kernel, dim3(64, 64), dim3(512), 0, stream,
                     Txp, Ty, W2s, b2f, W3f, b3f, out);
}